// Round 14
// baseline (450.453 us; speedup 1.0000x reference)
//
#include <hip/hip_runtime.h>
#include <math.h>

#define IN_USER 256
#define IN_ITEM 128
#define HID 128
#define OUTF 64
#define NRANGE 8
#define NCHUNK 16
#define MAXRB 12544   // NP/NRANGE for nmax=100000 (NP=100352)

typedef unsigned short u16;
typedef unsigned int u32;
typedef __attribute__((ext_vector_type(8))) __bf16 bf16x8;
typedef __attribute__((ext_vector_type(4))) float f32x4;

__device__ __forceinline__ u16 f2bf(float f) {
    union { float f; u32 u; } c; c.f = f;
    return (u16)((c.u + 0x7fffu + ((c.u >> 16) & 1u)) >> 16);
}
__device__ __forceinline__ u32 pack2(float a, float b) {
    return (u32)f2bf(a) | ((u32)f2bf(b) << 16);
}

// ---- Phase A: per-(range,chunk,array) histogram, LDS-privatized ----
// 512 threads/block, NCHUNK=16 -> 768 blocks (R12 had 384@256thr, 7% occ).
__global__ __launch_bounds__(512) void hist_ranges(
        const int* __restrict__ a0, int e0, const int* __restrict__ a1, int e1,
        const int* __restrict__ a2, int e2, const int* __restrict__ a3, int e3,
        const int* __restrict__ a4, int e4, const int* __restrict__ a5, int e5,
        int* __restrict__ hist, int NP, int RB) {
    __shared__ int h[MAXRB];
    const int a = blockIdx.z;
    const int* arr; int E;
    switch (a) {
        case 0: arr = a0; E = e0; break;
        case 1: arr = a1; E = e1; break;
        case 2: arr = a2; E = e2; break;
        case 3: arr = a3; E = e3; break;
        case 4: arr = a4; E = e4; break;
        default: arr = a5; E = e5; break;
    }
    const int c = blockIdx.y;
    const int lo = blockIdx.x * RB;
    const u32 rbu = (u32)RB;
    const int tid = threadIdx.x;
    for (int i = tid; i < RB; i += 512) h[i] = 0;
    __syncthreads();
    const int ec = (((E + NCHUNK - 1) / NCHUNK) + 3) & ~3;
    const int s0 = c * ec;
    const int s1 = (s0 + ec) < E ? (s0 + ec) : E;
    if (s1 > s0) {
        const int n4 = (s1 - s0) >> 2;
        const int4* p4 = reinterpret_cast<const int4*>(arr + s0);
        for (int i = tid; i < n4; i += 512) {
            const int4 A = p4[i];
            u32 ux = (u32)(A.x - lo); if (ux < rbu) atomicAdd(&h[ux], 1);
            u32 uy = (u32)(A.y - lo); if (uy < rbu) atomicAdd(&h[uy], 1);
            u32 uz = (u32)(A.z - lo); if (uz < rbu) atomicAdd(&h[uz], 1);
            u32 uw = (u32)(A.w - lo); if (uw < rbu) atomicAdd(&h[uw], 1);
        }
        for (int j = s0 + (n4 << 2) + tid; j < s1; j += 512) {
            const u32 u = (u32)(arr[j] - lo);
            if (u < rbu) atomicAdd(&h[u], 1);
        }
    }
    __syncthreads();
    int* out = hist + ((size_t)a * NCHUNK + c) * NP + lo;
    for (int i = tid; i < RB; i += 512) out[i] = h[i];
}

// ---- Phase B: deg + inv fused; dst-hists -> exclusive per-chunk prefix ----
__global__ __launch_bounds__(256) void hist_reduce(
        int* __restrict__ hist, int* __restrict__ deg,
        float* __restrict__ inv, int NP) {
    const int a = blockIdx.y;
    const int v = blockIdx.x * 256 + threadIdx.x;
    if (v >= NP) return;
    int* h = hist + (size_t)a * NCHUNK * NP + v;
    int s = 0;
#pragma unroll
    for (int c = 0; c < NCHUNK; ++c) {
        const int t = h[(size_t)c * NP];
        if (a & 1) h[(size_t)c * NP] = s;   // dst arrays: per-chunk offset
        s += t;
    }
    deg[(size_t)a * NP + v] = s;
    inv[(size_t)a * NP + v] = 1.0f / sqrtf((float)(s > 1 ? s : 1));
}

// ------- exclusive scan over raw dst-degrees (3 relations batched) ----
__global__ __launch_bounds__(256) void scan_part(
        const int* __restrict__ d0, const int* __restrict__ d1,
        const int* __restrict__ d2, int n0, int n1, int n2,
        int* __restrict__ partial, int nblk) {
    const int rel = blockIdx.y;
    const int* deg = rel == 0 ? d0 : (rel == 1 ? d1 : d2);
    const int n = rel == 0 ? n0 : (rel == 1 ? n1 : n2);
    const int base = blockIdx.x * 1024 + threadIdx.x * 4;
    int s = 0;
#pragma unroll
    for (int i = 0; i < 4; ++i) {
        const int idx = base + i;
        if (idx < n) s += deg[idx];
    }
    __shared__ int red[256];
    red[threadIdx.x] = s;
    __syncthreads();
#pragma unroll
    for (int off = 128; off > 0; off >>= 1) {
        if (threadIdx.x < off) red[threadIdx.x] += red[threadIdx.x + off];
        __syncthreads();
    }
    if (threadIdx.x == 0) partial[rel * nblk + blockIdx.x] = red[0];
}

__global__ __launch_bounds__(128) void scan_mid(int* __restrict__ partial, int nblk) {
    __shared__ int sc[128];
    const int rel = blockIdx.x;
    const int t = threadIdx.x;
    const int v = (t < nblk) ? partial[rel * nblk + t] : 0;
    sc[t] = v;
    __syncthreads();
    for (int off = 1; off < 128; off <<= 1) {
        const int u = (t >= off) ? sc[t - off] : 0;
        __syncthreads();
        sc[t] += u;
        __syncthreads();
    }
    if (t < nblk) partial[rel * nblk + t] = sc[t] - v;
}

__global__ __launch_bounds__(256) void scan_final(
        const int* __restrict__ d0, const int* __restrict__ d1,
        const int* __restrict__ d2, int n0, int n1, int n2,
        const int* __restrict__ partial,
        int* __restrict__ c0, int* __restrict__ c1, int* __restrict__ c2,
        int nblk) {
    const int rel = blockIdx.y;
    const int* deg = rel == 0 ? d0 : (rel == 1 ? d1 : d2);
    int* cur = rel == 0 ? c0 : (rel == 1 ? c1 : c2);
    const int n = rel == 0 ? n0 : (rel == 1 ? n1 : n2);
    const int base = blockIdx.x * 1024 + threadIdx.x * 4;
    int v[4];
    int s = 0;
#pragma unroll
    for (int i = 0; i < 4; ++i) {
        const int idx = base + i;
        v[i] = (idx < n) ? deg[idx] : 0;
        s += v[i];
    }
    __shared__ int sc[256];
    sc[threadIdx.x] = s;
    __syncthreads();
    for (int off = 1; off < 256; off <<= 1) {
        const int u = (threadIdx.x >= off) ? sc[threadIdx.x - off] : 0;
        __syncthreads();
        sc[threadIdx.x] += u;
        __syncthreads();
    }
    int run = (threadIdx.x == 0 ? 0 : sc[threadIdx.x - 1]) + partial[rel * nblk + blockIdx.x];
#pragma unroll
    for (int i = 0; i < 4; ++i) {
        const int idx = base + i;
        if (idx < n) cur[idx] = run;   // cursor = segment START (unpadded)
        run += v[i];
    }
}

// ---- Phase C: CSR fill, per-(range,chunk,rel) block, LDS cursor ----
__global__ __launch_bounds__(512) void fill_ranges(
        const int* __restrict__ s0p, const int* __restrict__ d0p, int e0,
        const int* __restrict__ s1p, const int* __restrict__ d1p, int e1,
        const int* __restrict__ s2p, const int* __restrict__ d2p, int e2,
        const int* __restrict__ cursor, const int* __restrict__ hist,
        int NP, int RB,
        int* __restrict__ csrbase, int off1, int off2) {
    __shared__ int cur[MAXRB];
    const int rel = blockIdx.z;
    const int* src = rel == 0 ? s0p : (rel == 1 ? s1p : s2p);
    const int* dst = rel == 0 ? d0p : (rel == 1 ? d1p : d2p);
    const int E = rel == 0 ? e0 : (rel == 1 ? e1 : e2);
    int* csr = csrbase + (rel == 0 ? 0 : (rel == 1 ? off1 : off2));
    const int c = blockIdx.y;
    const int lo = blockIdx.x * RB;
    const u32 rbu = (u32)RB;
    const int tid = threadIdx.x;
    const int* gc = cursor + (size_t)rel * NP + lo;
    const int* go = hist + ((size_t)(2 * rel + 1) * NCHUNK + c) * NP + lo;
    for (int i = tid; i < RB; i += 512) cur[i] = gc[i] + go[i];
    __syncthreads();
    const int ec = (((E + NCHUNK - 1) / NCHUNK) + 3) & ~3;
    const int s0 = c * ec;
    const int s1 = (s0 + ec) < E ? (s0 + ec) : E;
    if (s1 > s0) {
        const int n4 = (s1 - s0) >> 2;
        const int4* d4 = reinterpret_cast<const int4*>(dst + s0);
        const int4* s4 = reinterpret_cast<const int4*>(src + s0);
        for (int i = tid; i < n4; i += 512) {
            const int4 D = d4[i], S = s4[i];
            u32 ux = (u32)(D.x - lo); if (ux < rbu) { int p = atomicAdd(&cur[ux], 1); csr[p] = S.x; }
            u32 uy = (u32)(D.y - lo); if (uy < rbu) { int p = atomicAdd(&cur[uy], 1); csr[p] = S.y; }
            u32 uz = (u32)(D.z - lo); if (uz < rbu) { int p = atomicAdd(&cur[uz], 1); csr[p] = S.z; }
            u32 uw = (u32)(D.w - lo); if (uw < rbu) { int p = atomicAdd(&cur[uw], 1); csr[p] = S.w; }
        }
        for (int j = s0 + (n4 << 2) + tid; j < s1; j += 512) {
            const u32 u = (u32)(dst[j] - lo);
            if (u < rbu) { const int p = atomicAdd(&cur[u], 1); csr[p] = src[j]; }
        }
    }
}

// -------- all weight transposes in ONE kernel (bf16 [N][K] from [K][N]) ---
__global__ __launch_bounds__(256) void wt_all(
        u16* __restrict__ Wt1u, const float* __restrict__ W1_rates,
        const float* __restrict__ W1_fol,
        u16* __restrict__ Wt1i, const float* __restrict__ W1_rated,
        u16* __restrict__ Wt2u, const float* __restrict__ W2_rates,
        const float* __restrict__ W2_fol,
        u16* __restrict__ Wt2i, const float* __restrict__ W2_rated) {
    int i = blockIdx.x * 256 + threadIdx.x;
    if (i < 65536) {                      // Wt1u [256][256]
        const int n = i >> 8, k = i & 255;
        const float v = (n < 128) ? W1_rates[k * 128 + n] : W1_fol[k * 128 + (n - 128)];
        Wt1u[(size_t)n * 256 + k] = f2bf(v);
        return;
    }
    i -= 65536;
    if (i < 16384) {                      // Wt1i [128][128]
        const int n = i >> 7, k = i & 127;
        Wt1i[(size_t)n * 128 + k] = f2bf(W1_rated[k * 128 + n]);
        return;
    }
    i -= 16384;
    if (i < 16384) {                      // Wt2u [128][128]
        const int n = i >> 7, k = i & 127;
        const float v = (n < 64) ? W2_rates[k * 64 + n] : W2_fol[k * 64 + (n - 64)];
        Wt2u[(size_t)n * 128 + k] = f2bf(v);
        return;
    }
    i -= 16384;
    if (i < 8192) {                       // Wt2i [64][128]
        const int n = i >> 7, k = i & 127;
        Wt2i[(size_t)n * 128 + k] = f2bf(W2_rated[k * 64 + n]);
    }
}

// -------- MFMA GEMM: T = bf16((X @ Wt^T) * inv[:,None]) --------
template<int K, int BN, bool A_BF16>
__global__ __launch_bounds__(BN * 2) void gemm_mfma(
        const void* __restrict__ Xv, const u16* __restrict__ Wt,
        const float* __restrict__ invA, const float* __restrict__ invB,
        int nsplit, u16* __restrict__ T, int M, int TN) {
    constexpr int BLK = BN * 2;
    constexpr int WN = BN / 64;
    constexpr int CA = 1024 / BLK;
    constexpr int CB = (BN * 8) / BLK;
    __shared__ u16 lA[128 * 64];
    __shared__ u16 lB[BN * 64];

    const int tid = threadIdx.x;
    const int row0 = blockIdx.x * 128;
    const int col0 = blockIdx.y * BN;
    const int wid = tid >> 6, lane = tid & 63;
    const int wm = wid / WN, wn = wid % WN;
    const int l15 = lane & 15, lhi = lane >> 4;

    f32x4 acc[4][4] = {};

    for (int kk = 0; kk < K; kk += 64) {
        __syncthreads();
#pragma unroll
        for (int c = 0; c < CA; ++c) {
            const int cid = tid + c * BLK;
            const int row = cid >> 3, kc = cid & 7;
            const int grow = row0 + row;
            uint4 u = make_uint4(0, 0, 0, 0);
            if (A_BF16) {
                if (grow < M)
                    u = *reinterpret_cast<const uint4*>(
                        (const u16*)Xv + (size_t)grow * K + kk + kc * 8);
            } else {
                if (grow < M) {
                    const float* xp = (const float*)Xv + (size_t)grow * K + kk + kc * 8;
                    const float4 v0 = *reinterpret_cast<const float4*>(xp);
                    const float4 v1 = *reinterpret_cast<const float4*>(xp + 4);
                    u.x = pack2(v0.x, v0.y); u.y = pack2(v0.z, v0.w);
                    u.z = pack2(v1.x, v1.y); u.w = pack2(v1.z, v1.w);
                }
            }
            const int e = row * 64 + ((kc ^ (row & 7)) << 3);
            *reinterpret_cast<uint4*>(&lA[e]) = u;
        }
#pragma unroll
        for (int c = 0; c < CB; ++c) {
            const int cid = tid + c * BLK;
            const int n = cid >> 3, kc = cid & 7;
            const uint4 u = *reinterpret_cast<const uint4*>(
                Wt + (size_t)(col0 + n) * K + kk + kc * 8);
            const int e = n * 64 + ((kc ^ (n & 7)) << 3);
            *reinterpret_cast<uint4*>(&lB[e]) = u;
        }
        __syncthreads();
#pragma unroll
        for (int ks = 0; ks < 2; ++ks) {
            const int cb = ks * 4 + lhi;
            bf16x8 af[4], bfr[4];
#pragma unroll
            for (int fm = 0; fm < 4; ++fm) {
                const int r = wm * 64 + fm * 16 + l15;
                const uint4 u = *reinterpret_cast<const uint4*>(
                    &lA[r * 64 + ((cb ^ (r & 7)) << 3)]);
                af[fm] = __builtin_bit_cast(bf16x8, u);
            }
#pragma unroll
            for (int fn = 0; fn < 4; ++fn) {
                const int r = wn * 64 + fn * 16 + l15;
                const uint4 u = *reinterpret_cast<const uint4*>(
                    &lB[r * 64 + ((cb ^ (r & 7)) << 3)]);
                bfr[fn] = __builtin_bit_cast(bf16x8, u);
            }
#pragma unroll
            for (int fm = 0; fm < 4; ++fm)
#pragma unroll
                for (int fn = 0; fn < 4; ++fn)
                    acc[fm][fn] = __builtin_amdgcn_mfma_f32_16x16x32_bf16(
                        af[fm], bfr[fn], acc[fm][fn], 0, 0, 0);
        }
    }

    const int colw = col0 + wn * 64;
    const float* invp = (colw >= nsplit) ? invB : invA;
#pragma unroll
    for (int fm = 0; fm < 4; ++fm) {
#pragma unroll
        for (int r4 = 0; r4 < 4; ++r4) {
            const int grow = row0 + wm * 64 + fm * 16 + lhi * 4 + r4;
            if (grow < M) {
                const float s = invp[grow];
#pragma unroll
                for (int fn = 0; fn < 4; ++fn) {
                    const int col = colw + fn * 16 + l15;
                    T[(size_t)grow * TN + col] = f2bf(acc[fm][fn][r4] * s);
                }
            }
        }
    }
}

// -------- pull-aggregation over bf16 T, one wave per dst node -----------
// CSR indices are wave-uniform: readfirstlane hoists the row base to SGPRs
// so each edge is ONE global_load with scalar base + lane offset. Tail
// masked to zero row Z.
template<int F>
__device__ __forceinline__ void gather_rel(
        const u16* __restrict__ T, int strideT, int offT,
        const int* __restrict__ csr, int beg, int cnt, int Z, int lane,
        float& s0, float& s1) {
    const int* cp = csr + beg;
    const int loff = (F == 128) ? lane * 2 : lane;
    for (int e = 0; e < cnt; e += 8) {
        int idx[8];
#pragma unroll
        for (int i = 0; i < 8; ++i) {
            const int t = cp[e + i];
            idx[i] = __builtin_amdgcn_readfirstlane((e + i < cnt) ? t : Z);
        }
        if (F == 128) {
            u32 v[8];
#pragma unroll
            for (int i = 0; i < 8; ++i)
                v[i] = *reinterpret_cast<const u32*>(
                    T + (size_t)idx[i] * strideT + offT + loff);
#pragma unroll
            for (int i = 0; i < 8; ++i) {
                union { u32 u; float f; } lo, hi;
                lo.u = v[i] << 16;
                hi.u = v[i] & 0xffff0000u;
                s0 += lo.f; s1 += hi.f;
            }
        } else {
            u16 v[8];
#pragma unroll
            for (int i = 0; i < 8; ++i)
                v[i] = T[(size_t)idx[i] * strideT + offT + loff];
#pragma unroll
            for (int i = 0; i < 8; ++i) {
                union { u32 u; float f; } c;
                c.u = ((u32)v[i]) << 16;
                s0 += c.f;
            }
        }
    }
}

template<int F, bool TWO, bool RELU, bool BF16OUT>
__global__ __launch_bounds__(256) void gather(
        const u16* __restrict__ Ta, int strideA, int offA,
        const int* __restrict__ csrA, const int* __restrict__ curA,
        const int* __restrict__ degA, const float* __restrict__ invA,
        const float* __restrict__ biasA,
        const u16* __restrict__ Tb, int strideB, int offB,
        const int* __restrict__ csrB, const int* __restrict__ curB,
        const int* __restrict__ degB, const float* __restrict__ invB,
        const float* __restrict__ biasB,
        void* __restrict__ outv, int Z, int n) {
    const int wid = (blockIdx.x * 256 + threadIdx.x) >> 6;
    const int lane = threadIdx.x & 63;
    if (wid >= n) return;
    float r0, r1 = 0.f;
    {
        const int cnt = degA[wid];
        const int beg = curA[wid];   // cursor = segment start
        float s0 = 0.f, s1 = 0.f;
        gather_rel<F>(Ta, strideA, offA, csrA, beg, cnt, Z, lane, s0, s1);
        const float a = invA[wid];
        if (F == 128) {
            const float2 b = *reinterpret_cast<const float2*>(biasA + lane * 2);
            r0 = s0 * a + b.x; r1 = s1 * a + b.y;
        } else {
            r0 = s0 * a + biasA[lane];
        }
    }
    if (TWO) {
        const int cnt = degB[wid];
        const int beg = curB[wid];
        float s0 = 0.f, s1 = 0.f;
        gather_rel<F>(Tb, strideB, offB, csrB, beg, cnt, Z, lane, s0, s1);
        const float a = invB[wid];
        if (F == 128) {
            const float2 b = *reinterpret_cast<const float2*>(biasB + lane * 2);
            r0 += s0 * a + b.x; r1 += s1 * a + b.y;
        } else {
            r0 += s0 * a + biasB[lane];
        }
    }
    if (RELU) { r0 = fmaxf(r0, 0.f); r1 = fmaxf(r1, 0.f); }
    if (BF16OUT) {
        if (F == 128)
            ((u32*)outv)[(size_t)wid * 64 + lane] = pack2(r0, r1);
        else
            ((u16*)outv)[(size_t)wid * 64 + lane] = f2bf(r0);
    } else {
        if (F == 128) {
            float2 o; o.x = r0; o.y = r1;
            *reinterpret_cast<float2*>((float*)outv + (size_t)wid * 128 + lane * 2) = o;
        } else {
            ((float*)outv)[(size_t)wid * 64 + lane] = r0;
        }
    }
}

extern "C" void kernel_launch(void* const* d_in, const int* in_sizes, int n_in,
                              void* d_out, int out_size, void* d_ws, size_t ws_size,
                              hipStream_t stream) {
    const float* feat_user = (const float*)d_in[0];
    const float* feat_item = (const float*)d_in[1];
    const int* rates_src = (const int*)d_in[2];
    const int* rates_dst = (const int*)d_in[3];
    const int* rated_src = (const int*)d_in[4];
    const int* rated_dst = (const int*)d_in[5];
    const int* fol_src   = (const int*)d_in[6];
    const int* fol_dst   = (const int*)d_in[7];
    const float* W1_rates = (const float*)d_in[8];
    const float* b1_rates = (const float*)d_in[9];
    const float* W1_rated = (const float*)d_in[10];
    const float* b1_rated = (const float*)d_in[11];
    const float* W1_fol   = (const float*)d_in[12];
    const float* b1_fol   = (const float*)d_in[13];
    const float* W2_rates = (const float*)d_in[14];
    const float* b2_rates = (const float*)d_in[15];
    const float* W2_rated = (const float*)d_in[16];
    const float* b2_rated = (const float*)d_in[17];
    const float* W2_fol   = (const float*)d_in[18];
    const float* b2_fol   = (const float*)d_in[19];

    const int n_user = in_sizes[0] / IN_USER;
    const int n_item = in_sizes[1] / IN_ITEM;
    const int E0 = in_sizes[2];
    const int E1 = in_sizes[4];
    const int E2 = in_sizes[6];
    const int nmax = n_user > n_item ? n_user : n_item;
    const int Z = nmax;   // zero-row index (tail-mask target)

    // ---- workspace layout ----
    const size_t NP = ((size_t)(nmax + 1023) / 1024) * 1024;   // 100352
    int*   deg     = (int*)d_ws;                   // [6][NP]
    float* inv     = (float*)(deg + 6 * NP);       // [6][NP]
    int*   cursor  = (int*)(inv + 6 * NP);         // [3][NP]  (segment starts)
    int*   partial = cursor + 3 * NP;              // [3][128]
    int*   csr  = partial + 3 * 128;               // [E0+E1+E2] (unpadded)
    int*   csr0 = csr;
    int*   csr1 = csr + E0;
    int*   csr2 = csr + E0 + E1;
    u16* Wt1u = (u16*)(csr + E0 + E1 + E2);        // [256][256]
    u16* Wt1i = Wt1u + 256 * 256;                  // [128][128]
    u16* Wt2u = Wt1i + 128 * 128;                  // [128][128]
    u16* Wt2i = Wt2u + 128 * 128;                  // [64][128]
    u16* t1u  = Wt2i + 64 * 128;                   // [nmax+1][256] bf16
    u16* t1i  = t1u + (size_t)(nmax + 1) * 256;    // [nmax+1][128] bf16
    u16* aggU = t1i + (size_t)(nmax + 1) * 128;    // [n_user][128] bf16
    u16* aggI = aggU + (size_t)nmax * 128;         // [n_item][128] bf16
    u16* t2u  = t1i;   // alias: t1i dead after user_L1 gather
    u16* t2i  = t1u;   // alias: t1u dead after user_L1 gather
    // hist[6][NCHUNK][NP] aliases t1u's first 38.5MB (dead before L1 GEMM;
    // t1u's Z row at byte 51.2MB is beyond the hist region)
    int* hist = (int*)t1u;

    float* o_user = (float*)d_out;
    float* o_item = o_user + (size_t)n_user * OUTF;

    hipMemsetAsync(t1u + (size_t)Z * 256, 0, 512, stream);   // beyond hist area
    hipMemsetAsync(t1i + (size_t)Z * 128, 0, 256, stream);   // == t2u Z row

    // array idx: 0=rates_src(user) 1=rates_dst(item) 2=rated_src(item)
    //            3=rated_dst(user) 4=fol_src(user)   5=fol_dst(user)
    const int RB = (int)(NP / NRANGE);   // 12544 == MAXRB
    hist_ranges<<<dim3(NRANGE, NCHUNK, 6), 512, 0, stream>>>(
        rates_src, E0, rates_dst, E0, rated_src, E1,
        rated_dst, E1, fol_src, E2, fol_dst, E2, hist, (int)NP, RB);
    hist_reduce<<<dim3((int)(NP + 255) / 256, 6), 256, 0, stream>>>(
        hist, deg, inv, (int)NP);

    wt_all<<<(65536 + 16384 + 16384 + 8192 + 255) / 256, 256, 0, stream>>>(
        Wt1u, W1_rates, W1_fol, Wt1i, W1_rated,
        Wt2u, W2_rates, W2_fol, Wt2i, W2_rated);

    // ---- CSR build (by destination, unpadded segments) ----
    const int nblk = (int)(NP / 1024);
    scan_part<<<dim3(nblk, 3), 256, 0, stream>>>(
        deg + 1 * NP, deg + 3 * NP, deg + 5 * NP, n_item, n_user, n_user, partial, nblk);
    scan_mid<<<3, 128, 0, stream>>>(partial, nblk);
    scan_final<<<dim3(nblk, 3), 256, 0, stream>>>(
        deg + 1 * NP, deg + 3 * NP, deg + 5 * NP, n_item, n_user, n_user, partial,
        cursor + 0 * NP, cursor + 1 * NP, cursor + 2 * NP, nblk);
    fill_ranges<<<dim3(NRANGE, NCHUNK, 3), 512, 0, stream>>>(
        rates_src, rates_dst, E0, rated_src, rated_dst, E1,
        fol_src, fol_dst, E2, cursor, hist, (int)NP, RB, csr, E0, E0 + E1);

    const int gbU = (n_user + 127) / 128;
    const int gbI = (n_item + 127) / 128;
    const int gwU = (n_user * 64 + 255) / 256;
    const int gwI = (n_item * 64 + 255) / 256;

    // ---- layer 1 GEMMs (fused user: rates|fol -> t1u[.,0:128 | 128:256]) --
    gemm_mfma<256, 128, false><<<dim3(gbU, 2), 256, 0, stream>>>(
        feat_user, Wt1u, inv + 0 * NP, inv + 4 * NP, 128, t1u, n_user, 256);
    gemm_mfma<128, 128, false><<<dim3(gbI, 1), 256, 0, stream>>>(
        feat_item, Wt1i, inv + 2 * NP, inv + 2 * NP, 1 << 30, t1i, n_item, 128);

    // ---- layer 1 gathers ----
    gather<128, false, true, true><<<gwI, 256, 0, stream>>>(
        t1u, 256, 0, csr0, cursor + 0 * NP, deg + 1 * NP, inv + 1 * NP, b1_rates,
        nullptr, 0, 0, nullptr, nullptr, nullptr, nullptr, nullptr,
        aggI, Z, n_item);
    gather<128, true, true, true><<<gwU, 256, 0, stream>>>(
        t1i, 128, 0, csr1, cursor + 1 * NP, deg + 3 * NP, inv + 3 * NP, b1_rated,
        t1u, 256, 128, csr2, cursor + 2 * NP, deg + 5 * NP, inv + 5 * NP, b1_fol,
        aggU, Z, n_user);

    // t2i (= t1u region, stride 64) Z row: slot held live t1u data until now
    hipMemsetAsync(t2i + (size_t)Z * 64, 0, 128, stream);

    // ---- layer 2 GEMMs ----
    gemm_mfma<128, 128, true><<<dim3(gbU, 1), 256, 0, stream>>>(
        aggU, Wt2u, inv + 0 * NP, inv + 4 * NP, 64, t2u, n_user, 128);
    gemm_mfma<128, 64, true><<<dim3(gbI, 1), 128, 0, stream>>>(
        aggI, Wt2i, inv + 2 * NP, inv + 2 * NP, 1 << 30, t2i, n_item, 64);

    // ---- layer 2 gathers (straight into d_out, fp32) ----
    gather<64, false, false, false><<<gwI, 256, 0, stream>>>(
        t2u, 128, 0, csr0, cursor + 0 * NP, deg + 1 * NP, inv + 1 * NP, b2_rates,
        nullptr, 0, 0, nullptr, nullptr, nullptr, nullptr, nullptr,
        o_item, Z, n_item);
    gather<64, true, false, false><<<gwU, 256, 0, stream>>>(
        t2i, 64, 0, csr1, cursor + 1 * NP, deg + 3 * NP, inv + 3 * NP, b2_rated,
        t2u, 128, 64, csr2, cursor + 2 * NP, deg + 5 * NP, inv + 5 * NP, b2_fol,
        o_user, Z, n_user);
}

// Round 15
// 449.213 us; speedup vs baseline: 1.0028x; 1.0028x over previous
//
#include <hip/hip_runtime.h>
#include <math.h>

#define IN_USER 256
#define IN_ITEM 128
#define HID 128
#define OUTF 64
#define NRANGE 8
#define NCHUNK 16
#define MAXRB 12544   // NP/NRANGE for nmax=100000 (NP=100352)

typedef unsigned short u16;
typedef unsigned int u32;
typedef __attribute__((ext_vector_type(8))) __bf16 bf16x8;
typedef __attribute__((ext_vector_type(4))) float f32x4;

__device__ __forceinline__ u16 f2bf(float f) {
    union { float f; u32 u; } c; c.f = f;
    return (u16)((c.u + 0x7fffu + ((c.u >> 16) & 1u)) >> 16);
}
__device__ __forceinline__ u32 pack2(float a, float b) {
    return (u32)f2bf(a) | ((u32)f2bf(b) << 16);
}

// ---- Phase A: per-(range,chunk,array) histogram, LDS-privatized ----
// 512 threads/block, NCHUNK=16 -> 768 blocks (R12 had 384@256thr, 7% occ).
__global__ __launch_bounds__(512) void hist_ranges(
        const int* __restrict__ a0, int e0, const int* __restrict__ a1, int e1,
        const int* __restrict__ a2, int e2, const int* __restrict__ a3, int e3,
        const int* __restrict__ a4, int e4, const int* __restrict__ a5, int e5,
        int* __restrict__ hist, int NP, int RB) {
    __shared__ int h[MAXRB];
    const int a = blockIdx.z;
    const int* arr; int E;
    switch (a) {
        case 0: arr = a0; E = e0; break;
        case 1: arr = a1; E = e1; break;
        case 2: arr = a2; E = e2; break;
        case 3: arr = a3; E = e3; break;
        case 4: arr = a4; E = e4; break;
        default: arr = a5; E = e5; break;
    }
    const int c = blockIdx.y;
    const int lo = blockIdx.x * RB;
    const u32 rbu = (u32)RB;
    const int tid = threadIdx.x;
    for (int i = tid; i < RB; i += 512) h[i] = 0;
    __syncthreads();
    const int ec = (((E + NCHUNK - 1) / NCHUNK) + 3) & ~3;
    const int s0 = c * ec;
    const int s1 = (s0 + ec) < E ? (s0 + ec) : E;
    if (s1 > s0) {
        const int n4 = (s1 - s0) >> 2;
        const int4* p4 = reinterpret_cast<const int4*>(arr + s0);
        for (int i = tid; i < n4; i += 512) {
            const int4 A = p4[i];
            u32 ux = (u32)(A.x - lo); if (ux < rbu) atomicAdd(&h[ux], 1);
            u32 uy = (u32)(A.y - lo); if (uy < rbu) atomicAdd(&h[uy], 1);
            u32 uz = (u32)(A.z - lo); if (uz < rbu) atomicAdd(&h[uz], 1);
            u32 uw = (u32)(A.w - lo); if (uw < rbu) atomicAdd(&h[uw], 1);
        }
        for (int j = s0 + (n4 << 2) + tid; j < s1; j += 512) {
            const u32 u = (u32)(arr[j] - lo);
            if (u < rbu) atomicAdd(&h[u], 1);
        }
    }
    __syncthreads();
    int* out = hist + ((size_t)a * NCHUNK + c) * NP + lo;
    for (int i = tid; i < RB; i += 512) out[i] = h[i];
}

// ---- Phase B: deg + inv fused; dst-hists -> exclusive per-chunk prefix ----
__global__ __launch_bounds__(256) void hist_reduce(
        int* __restrict__ hist, int* __restrict__ deg,
        float* __restrict__ inv, int NP) {
    const int a = blockIdx.y;
    const int v = blockIdx.x * 256 + threadIdx.x;
    if (v >= NP) return;
    int* h = hist + (size_t)a * NCHUNK * NP + v;
    int s = 0;
#pragma unroll
    for (int c = 0; c < NCHUNK; ++c) {
        const int t = h[(size_t)c * NP];
        if (a & 1) h[(size_t)c * NP] = s;   // dst arrays: per-chunk offset
        s += t;
    }
    deg[(size_t)a * NP + v] = s;
    inv[(size_t)a * NP + v] = 1.0f / sqrtf((float)(s > 1 ? s : 1));
}

// ------- exclusive scan over raw dst-degrees (3 relations batched) ----
__global__ __launch_bounds__(256) void scan_part(
        const int* __restrict__ d0, const int* __restrict__ d1,
        const int* __restrict__ d2, int n0, int n1, int n2,
        int* __restrict__ partial, int nblk) {
    const int rel = blockIdx.y;
    const int* deg = rel == 0 ? d0 : (rel == 1 ? d1 : d2);
    const int n = rel == 0 ? n0 : (rel == 1 ? n1 : n2);
    const int base = blockIdx.x * 1024 + threadIdx.x * 4;
    int s = 0;
#pragma unroll
    for (int i = 0; i < 4; ++i) {
        const int idx = base + i;
        if (idx < n) s += deg[idx];
    }
    __shared__ int red[256];
    red[threadIdx.x] = s;
    __syncthreads();
#pragma unroll
    for (int off = 128; off > 0; off >>= 1) {
        if (threadIdx.x < off) red[threadIdx.x] += red[threadIdx.x + off];
        __syncthreads();
    }
    if (threadIdx.x == 0) partial[rel * nblk + blockIdx.x] = red[0];
}

__global__ __launch_bounds__(128) void scan_mid(int* __restrict__ partial, int nblk) {
    __shared__ int sc[128];
    const int rel = blockIdx.x;
    const int t = threadIdx.x;
    const int v = (t < nblk) ? partial[rel * nblk + t] : 0;
    sc[t] = v;
    __syncthreads();
    for (int off = 1; off < 128; off <<= 1) {
        const int u = (t >= off) ? sc[t - off] : 0;
        __syncthreads();
        sc[t] += u;
        __syncthreads();
    }
    if (t < nblk) partial[rel * nblk + t] = sc[t] - v;
}

__global__ __launch_bounds__(256) void scan_final(
        const int* __restrict__ d0, const int* __restrict__ d1,
        const int* __restrict__ d2, int n0, int n1, int n2,
        const int* __restrict__ partial,
        int* __restrict__ c0, int* __restrict__ c1, int* __restrict__ c2,
        int nblk) {
    const int rel = blockIdx.y;
    const int* deg = rel == 0 ? d0 : (rel == 1 ? d1 : d2);
    int* cur = rel == 0 ? c0 : (rel == 1 ? c1 : c2);
    const int n = rel == 0 ? n0 : (rel == 1 ? n1 : n2);
    const int base = blockIdx.x * 1024 + threadIdx.x * 4;
    int v[4];
    int s = 0;
#pragma unroll
    for (int i = 0; i < 4; ++i) {
        const int idx = base + i;
        v[i] = (idx < n) ? deg[idx] : 0;
        s += v[i];
    }
    __shared__ int sc[256];
    sc[threadIdx.x] = s;
    __syncthreads();
    for (int off = 1; off < 256; off <<= 1) {
        const int u = (threadIdx.x >= off) ? sc[threadIdx.x - off] : 0;
        __syncthreads();
        sc[threadIdx.x] += u;
        __syncthreads();
    }
    int run = (threadIdx.x == 0 ? 0 : sc[threadIdx.x - 1]) + partial[rel * nblk + blockIdx.x];
#pragma unroll
    for (int i = 0; i < 4; ++i) {
        const int idx = base + i;
        if (idx < n) cur[idx] = run;   // cursor = segment START (unpadded)
        run += v[i];
    }
}

// ---- Phase C: CSR fill, per-(range,chunk,rel) block, LDS cursor ----
__global__ __launch_bounds__(512) void fill_ranges(
        const int* __restrict__ s0p, const int* __restrict__ d0p, int e0,
        const int* __restrict__ s1p, const int* __restrict__ d1p, int e1,
        const int* __restrict__ s2p, const int* __restrict__ d2p, int e2,
        const int* __restrict__ cursor, const int* __restrict__ hist,
        int NP, int RB,
        int* __restrict__ csrbase, int off1, int off2) {
    __shared__ int cur[MAXRB];
    const int rel = blockIdx.z;
    const int* src = rel == 0 ? s0p : (rel == 1 ? s1p : s2p);
    const int* dst = rel == 0 ? d0p : (rel == 1 ? d1p : d2p);
    const int E = rel == 0 ? e0 : (rel == 1 ? e1 : e2);
    int* csr = csrbase + (rel == 0 ? 0 : (rel == 1 ? off1 : off2));
    const int c = blockIdx.y;
    const int lo = blockIdx.x * RB;
    const u32 rbu = (u32)RB;
    const int tid = threadIdx.x;
    const int* gc = cursor + (size_t)rel * NP + lo;
    const int* go = hist + ((size_t)(2 * rel + 1) * NCHUNK + c) * NP + lo;
    for (int i = tid; i < RB; i += 512) cur[i] = gc[i] + go[i];
    __syncthreads();
    const int ec = (((E + NCHUNK - 1) / NCHUNK) + 3) & ~3;
    const int s0 = c * ec;
    const int s1 = (s0 + ec) < E ? (s0 + ec) : E;
    if (s1 > s0) {
        const int n4 = (s1 - s0) >> 2;
        const int4* d4 = reinterpret_cast<const int4*>(dst + s0);
        const int4* s4 = reinterpret_cast<const int4*>(src + s0);
        for (int i = tid; i < n4; i += 512) {
            const int4 D = d4[i], S = s4[i];
            u32 ux = (u32)(D.x - lo); if (ux < rbu) { int p = atomicAdd(&cur[ux], 1); csr[p] = S.x; }
            u32 uy = (u32)(D.y - lo); if (uy < rbu) { int p = atomicAdd(&cur[uy], 1); csr[p] = S.y; }
            u32 uz = (u32)(D.z - lo); if (uz < rbu) { int p = atomicAdd(&cur[uz], 1); csr[p] = S.z; }
            u32 uw = (u32)(D.w - lo); if (uw < rbu) { int p = atomicAdd(&cur[uw], 1); csr[p] = S.w; }
        }
        for (int j = s0 + (n4 << 2) + tid; j < s1; j += 512) {
            const u32 u = (u32)(dst[j] - lo);
            if (u < rbu) { const int p = atomicAdd(&cur[u], 1); csr[p] = src[j]; }
        }
    }
}

// -------- all weight transposes in ONE kernel (bf16 [N][K] from [K][N]) ---
__global__ __launch_bounds__(256) void wt_all(
        u16* __restrict__ Wt1u, const float* __restrict__ W1_rates,
        const float* __restrict__ W1_fol,
        u16* __restrict__ Wt1i, const float* __restrict__ W1_rated,
        u16* __restrict__ Wt2u, const float* __restrict__ W2_rates,
        const float* __restrict__ W2_fol,
        u16* __restrict__ Wt2i, const float* __restrict__ W2_rated) {
    int i = blockIdx.x * 256 + threadIdx.x;
    if (i < 65536) {                      // Wt1u [256][256]
        const int n = i >> 8, k = i & 255;
        const float v = (n < 128) ? W1_rates[k * 128 + n] : W1_fol[k * 128 + (n - 128)];
        Wt1u[(size_t)n * 256 + k] = f2bf(v);
        return;
    }
    i -= 65536;
    if (i < 16384) {                      // Wt1i [128][128]
        const int n = i >> 7, k = i & 127;
        Wt1i[(size_t)n * 128 + k] = f2bf(W1_rated[k * 128 + n]);
        return;
    }
    i -= 16384;
    if (i < 16384) {                      // Wt2u [128][128]
        const int n = i >> 7, k = i & 127;
        const float v = (n < 64) ? W2_rates[k * 64 + n] : W2_fol[k * 64 + (n - 64)];
        Wt2u[(size_t)n * 128 + k] = f2bf(v);
        return;
    }
    i -= 16384;
    if (i < 8192) {                       // Wt2i [64][128]
        const int n = i >> 7, k = i & 127;
        Wt2i[(size_t)n * 128 + k] = f2bf(W2_rated[k * 64 + n]);
    }
}

// -------- MFMA GEMM: T = bf16((X @ Wt^T) * inv[:,None]) --------
template<int K, int BN, bool A_BF16>
__global__ __launch_bounds__(BN * 2) void gemm_mfma(
        const void* __restrict__ Xv, const u16* __restrict__ Wt,
        const float* __restrict__ invA, const float* __restrict__ invB,
        int nsplit, u16* __restrict__ T, int M, int TN) {
    constexpr int BLK = BN * 2;
    constexpr int WN = BN / 64;
    constexpr int CA = 1024 / BLK;
    constexpr int CB = (BN * 8) / BLK;
    __shared__ u16 lA[128 * 64];
    __shared__ u16 lB[BN * 64];

    const int tid = threadIdx.x;
    const int row0 = blockIdx.x * 128;
    const int col0 = blockIdx.y * BN;
    const int wid = tid >> 6, lane = tid & 63;
    const int wm = wid / WN, wn = wid % WN;
    const int l15 = lane & 15, lhi = lane >> 4;

    f32x4 acc[4][4] = {};

    for (int kk = 0; kk < K; kk += 64) {
        __syncthreads();
#pragma unroll
        for (int c = 0; c < CA; ++c) {
            const int cid = tid + c * BLK;
            const int row = cid >> 3, kc = cid & 7;
            const int grow = row0 + row;
            uint4 u = make_uint4(0, 0, 0, 0);
            if (A_BF16) {
                if (grow < M)
                    u = *reinterpret_cast<const uint4*>(
                        (const u16*)Xv + (size_t)grow * K + kk + kc * 8);
            } else {
                if (grow < M) {
                    const float* xp = (const float*)Xv + (size_t)grow * K + kk + kc * 8;
                    const float4 v0 = *reinterpret_cast<const float4*>(xp);
                    const float4 v1 = *reinterpret_cast<const float4*>(xp + 4);
                    u.x = pack2(v0.x, v0.y); u.y = pack2(v0.z, v0.w);
                    u.z = pack2(v1.x, v1.y); u.w = pack2(v1.z, v1.w);
                }
            }
            const int e = row * 64 + ((kc ^ (row & 7)) << 3);
            *reinterpret_cast<uint4*>(&lA[e]) = u;
        }
#pragma unroll
        for (int c = 0; c < CB; ++c) {
            const int cid = tid + c * BLK;
            const int n = cid >> 3, kc = cid & 7;
            const uint4 u = *reinterpret_cast<const uint4*>(
                Wt + (size_t)(col0 + n) * K + kk + kc * 8);
            const int e = n * 64 + ((kc ^ (n & 7)) << 3);
            *reinterpret_cast<uint4*>(&lB[e]) = u;
        }
        __syncthreads();
#pragma unroll
        for (int ks = 0; ks < 2; ++ks) {
            const int cb = ks * 4 + lhi;
            bf16x8 af[4], bfr[4];
#pragma unroll
            for (int fm = 0; fm < 4; ++fm) {
                const int r = wm * 64 + fm * 16 + l15;
                const uint4 u = *reinterpret_cast<const uint4*>(
                    &lA[r * 64 + ((cb ^ (r & 7)) << 3)]);
                af[fm] = __builtin_bit_cast(bf16x8, u);
            }
#pragma unroll
            for (int fn = 0; fn < 4; ++fn) {
                const int r = wn * 64 + fn * 16 + l15;
                const uint4 u = *reinterpret_cast<const uint4*>(
                    &lB[r * 64 + ((cb ^ (r & 7)) << 3)]);
                bfr[fn] = __builtin_bit_cast(bf16x8, u);
            }
#pragma unroll
            for (int fm = 0; fm < 4; ++fm)
#pragma unroll
                for (int fn = 0; fn < 4; ++fn)
                    acc[fm][fn] = __builtin_amdgcn_mfma_f32_16x16x32_bf16(
                        af[fm], bfr[fn], acc[fm][fn], 0, 0, 0);
        }
    }

    const int colw = col0 + wn * 64;
    const float* invp = (colw >= nsplit) ? invB : invA;
#pragma unroll
    for (int fm = 0; fm < 4; ++fm) {
#pragma unroll
        for (int r4 = 0; r4 < 4; ++r4) {
            const int grow = row0 + wm * 64 + fm * 16 + lhi * 4 + r4;
            if (grow < M) {
                const float s = invp[grow];
#pragma unroll
                for (int fn = 0; fn < 4; ++fn) {
                    const int col = colw + fn * 16 + l15;
                    T[(size_t)grow * TN + col] = f2bf(acc[fm][fn][r4] * s);
                }
            }
        }
    }
}

// -------- pull-aggregation over bf16 T, one wave per dst node -----------
// CSR indices are wave-uniform: readfirstlane hoists the row base to SGPRs
// so each edge is ONE global_load with scalar base + lane offset. Tail
// masked to zero row Z.
template<int F>
__device__ __forceinline__ void gather_rel(
        const u16* __restrict__ T, int strideT, int offT,
        const int* __restrict__ csr, int beg, int cnt, int Z, int lane,
        float& s0, float& s1) {
    const int* cp = csr + beg;
    const int loff = (F == 128) ? lane * 2 : lane;
    for (int e = 0; e < cnt; e += 8) {
        int idx[8];
#pragma unroll
        for (int i = 0; i < 8; ++i) {
            const int t = cp[e + i];
            idx[i] = __builtin_amdgcn_readfirstlane((e + i < cnt) ? t : Z);
        }
        if (F == 128) {
            u32 v[8];
#pragma unroll
            for (int i = 0; i < 8; ++i)
                v[i] = *reinterpret_cast<const u32*>(
                    T + (size_t)idx[i] * strideT + offT + loff);
#pragma unroll
            for (int i = 0; i < 8; ++i) {
                union { u32 u; float f; } lo, hi;
                lo.u = v[i] << 16;
                hi.u = v[i] & 0xffff0000u;
                s0 += lo.f; s1 += hi.f;
            }
        } else {
            u16 v[8];
#pragma unroll
            for (int i = 0; i < 8; ++i)
                v[i] = T[(size_t)idx[i] * strideT + offT + loff];
#pragma unroll
            for (int i = 0; i < 8; ++i) {
                union { u32 u; float f; } c;
                c.u = ((u32)v[i]) << 16;
                s0 += c.f;
            }
        }
    }
}

template<int F, bool TWO, bool RELU, bool BF16OUT>
__global__ __launch_bounds__(256) void gather(
        const u16* __restrict__ Ta, int strideA, int offA,
        const int* __restrict__ csrA, const int* __restrict__ curA,
        const int* __restrict__ degA, const float* __restrict__ invA,
        const float* __restrict__ biasA,
        const u16* __restrict__ Tb, int strideB, int offB,
        const int* __restrict__ csrB, const int* __restrict__ curB,
        const int* __restrict__ degB, const float* __restrict__ invB,
        const float* __restrict__ biasB,
        void* __restrict__ outv, int Z, int n) {
    const int wid = (blockIdx.x * 256 + threadIdx.x) >> 6;
    const int lane = threadIdx.x & 63;
    if (wid >= n) return;
    float r0, r1 = 0.f;
    {
        const int cnt = degA[wid];
        const int beg = curA[wid];   // cursor = segment start
        float s0 = 0.f, s1 = 0.f;
        gather_rel<F>(Ta, strideA, offA, csrA, beg, cnt, Z, lane, s0, s1);
        const float a = invA[wid];
        if (F == 128) {
            const float2 b = *reinterpret_cast<const float2*>(biasA + lane * 2);
            r0 = s0 * a + b.x; r1 = s1 * a + b.y;
        } else {
            r0 = s0 * a + biasA[lane];
        }
    }
    if (TWO) {
        const int cnt = degB[wid];
        const int beg = curB[wid];
        float s0 = 0.f, s1 = 0.f;
        gather_rel<F>(Tb, strideB, offB, csrB, beg, cnt, Z, lane, s0, s1);
        const float a = invB[wid];
        if (F == 128) {
            const float2 b = *reinterpret_cast<const float2*>(biasB + lane * 2);
            r0 += s0 * a + b.x; r1 += s1 * a + b.y;
        } else {
            r0 += s0 * a + biasB[lane];
        }
    }
    if (RELU) { r0 = fmaxf(r0, 0.f); r1 = fmaxf(r1, 0.f); }
    if (BF16OUT) {
        if (F == 128)
            ((u32*)outv)[(size_t)wid * 64 + lane] = pack2(r0, r1);
        else
            ((u16*)outv)[(size_t)wid * 64 + lane] = f2bf(r0);
    } else {
        if (F == 128) {
            float2 o; o.x = r0; o.y = r1;
            *reinterpret_cast<float2*>((float*)outv + (size_t)wid * 128 + lane * 2) = o;
        } else {
            ((float*)outv)[(size_t)wid * 64 + lane] = r0;
        }
    }
}

extern "C" void kernel_launch(void* const* d_in, const int* in_sizes, int n_in,
                              void* d_out, int out_size, void* d_ws, size_t ws_size,
                              hipStream_t stream) {
    const float* feat_user = (const float*)d_in[0];
    const float* feat_item = (const float*)d_in[1];
    const int* rates_src = (const int*)d_in[2];
    const int* rates_dst = (const int*)d_in[3];
    const int* rated_src = (const int*)d_in[4];
    const int* rated_dst = (const int*)d_in[5];
    const int* fol_src   = (const int*)d_in[6];
    const int* fol_dst   = (const int*)d_in[7];
    const float* W1_rates = (const float*)d_in[8];
    const float* b1_rates = (const float*)d_in[9];
    const float* W1_rated = (const float*)d_in[10];
    const float* b1_rated = (const float*)d_in[11];
    const float* W1_fol   = (const float*)d_in[12];
    const float* b1_fol   = (const float*)d_in[13];
    const float* W2_rates = (const float*)d_in[14];
    const float* b2_rates = (const float*)d_in[15];
    const float* W2_rated = (const float*)d_in[16];
    const float* b2_rated = (const float*)d_in[17];
    const float* W2_fol   = (const float*)d_in[18];
    const float* b2_fol   = (const float*)d_in[19];

    const int n_user = in_sizes[0] / IN_USER;
    const int n_item = in_sizes[1] / IN_ITEM;
    const int E0 = in_sizes[2];
    const int E1 = in_sizes[4];
    const int E2 = in_sizes[6];
    const int nmax = n_user > n_item ? n_user : n_item;
    const int Z = nmax;   // zero-row index (tail-mask target)

    // ---- workspace layout ----
    const size_t NP = ((size_t)(nmax + 1023) / 1024) * 1024;   // 100352
    int*   deg     = (int*)d_ws;                   // [6][NP]
    float* inv     = (float*)(deg + 6 * NP);       // [6][NP]
    int*   cursor  = (int*)(inv + 6 * NP);         // [3][NP]  (segment starts)
    int*   partial = cursor + 3 * NP;              // [3][128]
    int*   csr  = partial + 3 * 128;               // [E0+E1+E2] (unpadded)
    int*   csr0 = csr;
    int*   csr1 = csr + E0;
    int*   csr2 = csr + E0 + E1;
    u16* Wt1u = (u16*)(csr + E0 + E1 + E2);        // [256][256]
    u16* Wt1i = Wt1u + 256 * 256;                  // [128][128]
    u16* Wt2u = Wt1i + 128 * 128;                  // [128][128]
    u16* Wt2i = Wt2u + 128 * 128;                  // [64][128]
    u16* t1u  = Wt2i + 64 * 128;                   // [nmax+1][256] bf16
    u16* t1i  = t1u + (size_t)(nmax + 1) * 256;    // [nmax+1][128] bf16
    u16* aggU = t1i + (size_t)(nmax + 1) * 128;    // [n_user][128] bf16
    u16* aggI = aggU + (size_t)nmax * 128;         // [n_item][128] bf16
    u16* t2u  = t1i;   // alias: t1i dead after user_L1 gather
    u16* t2i  = t1u;   // alias: t1u dead after user_L1 gather
    // hist[6][NCHUNK][NP] aliases t1u's first 38.5MB (dead before L1 GEMM;
    // t1u's Z row at byte 51.2MB is beyond the hist region)
    int* hist = (int*)t1u;

    float* o_user = (float*)d_out;
    float* o_item = o_user + (size_t)n_user * OUTF;

    hipMemsetAsync(t1u + (size_t)Z * 256, 0, 512, stream);   // beyond hist area
    hipMemsetAsync(t1i + (size_t)Z * 128, 0, 256, stream);   // == t2u Z row

    // array idx: 0=rates_src(user) 1=rates_dst(item) 2=rated_src(item)
    //            3=rated_dst(user) 4=fol_src(user)   5=fol_dst(user)
    const int RB = (int)(NP / NRANGE);   // 12544 == MAXRB
    hist_ranges<<<dim3(NRANGE, NCHUNK, 6), 512, 0, stream>>>(
        rates_src, E0, rates_dst, E0, rated_src, E1,
        rated_dst, E1, fol_src, E2, fol_dst, E2, hist, (int)NP, RB);
    hist_reduce<<<dim3((int)(NP + 255) / 256, 6), 256, 0, stream>>>(
        hist, deg, inv, (int)NP);

    wt_all<<<(65536 + 16384 + 16384 + 8192 + 255) / 256, 256, 0, stream>>>(
        Wt1u, W1_rates, W1_fol, Wt1i, W1_rated,
        Wt2u, W2_rates, W2_fol, Wt2i, W2_rated);

    // ---- CSR build (by destination, unpadded segments) ----
    const int nblk = (int)(NP / 1024);
    scan_part<<<dim3(nblk, 3), 256, 0, stream>>>(
        deg + 1 * NP, deg + 3 * NP, deg + 5 * NP, n_item, n_user, n_user, partial, nblk);
    scan_mid<<<3, 128, 0, stream>>>(partial, nblk);
    scan_final<<<dim3(nblk, 3), 256, 0, stream>>>(
        deg + 1 * NP, deg + 3 * NP, deg + 5 * NP, n_item, n_user, n_user, partial,
        cursor + 0 * NP, cursor + 1 * NP, cursor + 2 * NP, nblk);
    fill_ranges<<<dim3(NRANGE, NCHUNK, 3), 512, 0, stream>>>(
        rates_src, rates_dst, E0, rated_src, rated_dst, E1,
        fol_src, fol_dst, E2, cursor, hist, (int)NP, RB, csr, E0, E0 + E1);

    const int gbU = (n_user + 127) / 128;
    const int gbI = (n_item + 127) / 128;
    const int gwU = (n_user * 64 + 255) / 256;
    const int gwI = (n_item * 64 + 255) / 256;

    // ---- layer 1 GEMMs (fused user: rates|fol -> t1u[.,0:128 | 128:256]) --
    gemm_mfma<256, 128, false><<<dim3(gbU, 2), 256, 0, stream>>>(
        feat_user, Wt1u, inv + 0 * NP, inv + 4 * NP, 128, t1u, n_user, 256);
    gemm_mfma<128, 128, false><<<dim3(gbI, 1), 256, 0, stream>>>(
        feat_item, Wt1i, inv + 2 * NP, inv + 2 * NP, 1 << 30, t1i, n_item, 128);

    // ---- layer 1 gathers ----
    gather<128, false, true, true><<<gwI, 256, 0, stream>>>(
        t1u, 256, 0, csr0, cursor + 0 * NP, deg + 1 * NP, inv + 1 * NP, b1_rates,
        nullptr, 0, 0, nullptr, nullptr, nullptr, nullptr, nullptr,
        aggI, Z, n_item);
    gather<128, true, true, true><<<gwU, 256, 0, stream>>>(
        t1i, 128, 0, csr1, cursor + 1 * NP, deg + 3 * NP, inv + 3 * NP, b1_rated,
        t1u, 256, 128, csr2, cursor + 2 * NP, deg + 5 * NP, inv + 5 * NP, b1_fol,
        aggU, Z, n_user);

    // t2i (= t1u region, stride 64) Z row: slot held live t1u data until now
    hipMemsetAsync(t2i + (size_t)Z * 64, 0, 128, stream);

    // ---- layer 2 GEMMs ----
    gemm_mfma<128, 128, true><<<dim3(gbU, 1), 256, 0, stream>>>(
        aggU, Wt2u, inv + 0 * NP, inv + 4 * NP, 64, t2u, n_user, 128);
    gemm_mfma<128, 64, true><<<dim3(gbI, 1), 128, 0, stream>>>(
        aggI, Wt2i, inv + 2 * NP, inv + 2 * NP, 1 << 30, t2i, n_item, 64);

    // ---- layer 2 gathers (straight into d_out, fp32) ----
    gather<64, false, false, false><<<gwI, 256, 0, stream>>>(
        t2u, 128, 0, csr0, cursor + 0 * NP, deg + 1 * NP, inv + 1 * NP, b2_rates,
        nullptr, 0, 0, nullptr, nullptr, nullptr, nullptr, nullptr,
        o_item, Z, n_item);
    gather<64, true, false, false><<<gwU, 256, 0, stream>>>(
        t2i, 64, 0, csr1, cursor + 1 * NP, deg + 3 * NP, inv + 3 * NP, b2_rated,
        t2u, 128, 64, csr2, cursor + 2 * NP, deg + 5 * NP, inv + 5 * NP, b2_fol,
        o_user, Z, n_user);
}

// Round 16
// 398.556 us; speedup vs baseline: 1.1302x; 1.1271x over previous
//
#include <hip/hip_runtime.h>
#include <math.h>

#define IN_USER 256
#define IN_ITEM 128
#define HID 128
#define OUTF 64
#define NRANGE 8
#define NCHUNK 16
#define MAXRB 12544   // NP/NRANGE for nmax=100000 (NP=100352)

typedef unsigned short u16;
typedef unsigned int u32;
typedef __attribute__((ext_vector_type(8))) __bf16 bf16x8;
typedef __attribute__((ext_vector_type(4))) float f32x4;

__device__ __forceinline__ u16 f2bf(float f) {
    union { float f; u32 u; } c; c.f = f;
    return (u16)((c.u + 0x7fffu + ((c.u >> 16) & 1u)) >> 16);
}
__device__ __forceinline__ u32 pack2(float a, float b) {
    return (u32)f2bf(a) | ((u32)f2bf(b) << 16);
}

// ---- Phase A: per-(range,chunk,array) histogram, LDS-privatized ----
__global__ __launch_bounds__(512) void hist_ranges(
        const int* __restrict__ a0, int e0, const int* __restrict__ a1, int e1,
        const int* __restrict__ a2, int e2, const int* __restrict__ a3, int e3,
        const int* __restrict__ a4, int e4, const int* __restrict__ a5, int e5,
        int* __restrict__ hist, int NP, int RB) {
    __shared__ int h[MAXRB];
    const int a = blockIdx.z;
    const int* arr; int E;
    switch (a) {
        case 0: arr = a0; E = e0; break;
        case 1: arr = a1; E = e1; break;
        case 2: arr = a2; E = e2; break;
        case 3: arr = a3; E = e3; break;
        case 4: arr = a4; E = e4; break;
        default: arr = a5; E = e5; break;
    }
    const int c = blockIdx.y;
    const int lo = blockIdx.x * RB;
    const u32 rbu = (u32)RB;
    const int tid = threadIdx.x;
    for (int i = tid; i < RB; i += 512) h[i] = 0;
    __syncthreads();
    const int ec = (((E + NCHUNK - 1) / NCHUNK) + 3) & ~3;
    const int s0 = c * ec;
    const int s1 = (s0 + ec) < E ? (s0 + ec) : E;
    if (s1 > s0) {
        const int n4 = (s1 - s0) >> 2;
        const int4* p4 = reinterpret_cast<const int4*>(arr + s0);
        for (int i = tid; i < n4; i += 512) {
            const int4 A = p4[i];
            u32 ux = (u32)(A.x - lo); if (ux < rbu) atomicAdd(&h[ux], 1);
            u32 uy = (u32)(A.y - lo); if (uy < rbu) atomicAdd(&h[uy], 1);
            u32 uz = (u32)(A.z - lo); if (uz < rbu) atomicAdd(&h[uz], 1);
            u32 uw = (u32)(A.w - lo); if (uw < rbu) atomicAdd(&h[uw], 1);
        }
        for (int j = s0 + (n4 << 2) + tid; j < s1; j += 512) {
            const u32 u = (u32)(arr[j] - lo);
            if (u < rbu) atomicAdd(&h[u], 1);
        }
    }
    __syncthreads();
    int* out = hist + ((size_t)a * NCHUNK + c) * NP + lo;
    for (int i = tid; i < RB; i += 512) out[i] = h[i];
}

// ---- Phase B: deg + inv fused; dst-hists -> exclusive per-chunk prefix ----
__global__ __launch_bounds__(256) void hist_reduce(
        int* __restrict__ hist, int* __restrict__ deg,
        float* __restrict__ inv, int NP) {
    const int a = blockIdx.y;
    const int v = blockIdx.x * 256 + threadIdx.x;
    if (v >= NP) return;
    int* h = hist + (size_t)a * NCHUNK * NP + v;
    int s = 0;
#pragma unroll
    for (int c = 0; c < NCHUNK; ++c) {
        const int t = h[(size_t)c * NP];
        if (a & 1) h[(size_t)c * NP] = s;   // dst arrays: per-chunk offset
        s += t;
    }
    deg[(size_t)a * NP + v] = s;
    inv[(size_t)a * NP + v] = 1.0f / sqrtf((float)(s > 1 ? s : 1));
}

// ------- exclusive scan over raw dst-degrees (3 relations batched) ----
__global__ __launch_bounds__(256) void scan_part(
        const int* __restrict__ d0, const int* __restrict__ d1,
        const int* __restrict__ d2, int n0, int n1, int n2,
        int* __restrict__ partial, int nblk) {
    const int rel = blockIdx.y;
    const int* deg = rel == 0 ? d0 : (rel == 1 ? d1 : d2);
    const int n = rel == 0 ? n0 : (rel == 1 ? n1 : n2);
    const int base = blockIdx.x * 1024 + threadIdx.x * 4;
    int s = 0;
#pragma unroll
    for (int i = 0; i < 4; ++i) {
        const int idx = base + i;
        if (idx < n) s += deg[idx];
    }
    __shared__ int red[256];
    red[threadIdx.x] = s;
    __syncthreads();
#pragma unroll
    for (int off = 128; off > 0; off >>= 1) {
        if (threadIdx.x < off) red[threadIdx.x] += red[threadIdx.x + off];
        __syncthreads();
    }
    if (threadIdx.x == 0) partial[rel * nblk + blockIdx.x] = red[0];
}

__global__ __launch_bounds__(128) void scan_mid(int* __restrict__ partial, int nblk) {
    __shared__ int sc[128];
    const int rel = blockIdx.x;
    const int t = threadIdx.x;
    const int v = (t < nblk) ? partial[rel * nblk + t] : 0;
    sc[t] = v;
    __syncthreads();
    for (int off = 1; off < 128; off <<= 1) {
        const int u = (t >= off) ? sc[t - off] : 0;
        __syncthreads();
        sc[t] += u;
        __syncthreads();
    }
    if (t < nblk) partial[rel * nblk + t] = sc[t] - v;
}

__global__ __launch_bounds__(256) void scan_final(
        const int* __restrict__ d0, const int* __restrict__ d1,
        const int* __restrict__ d2, int n0, int n1, int n2,
        const int* __restrict__ partial,
        int* __restrict__ c0, int* __restrict__ c1, int* __restrict__ c2,
        int nblk) {
    const int rel = blockIdx.y;
    const int* deg = rel == 0 ? d0 : (rel == 1 ? d1 : d2);
    int* cur = rel == 0 ? c0 : (rel == 1 ? c1 : c2);
    const int n = rel == 0 ? n0 : (rel == 1 ? n1 : n2);
    const int base = blockIdx.x * 1024 + threadIdx.x * 4;
    int v[4];
    int s = 0;
#pragma unroll
    for (int i = 0; i < 4; ++i) {
        const int idx = base + i;
        v[i] = (idx < n) ? deg[idx] : 0;
        s += v[i];
    }
    __shared__ int sc[256];
    sc[threadIdx.x] = s;
    __syncthreads();
    for (int off = 1; off < 256; off <<= 1) {
        const int u = (threadIdx.x >= off) ? sc[threadIdx.x - off] : 0;
        __syncthreads();
        sc[threadIdx.x] += u;
        __syncthreads();
    }
    int run = (threadIdx.x == 0 ? 0 : sc[threadIdx.x - 1]) + partial[rel * nblk + blockIdx.x];
#pragma unroll
    for (int i = 0; i < 4; ++i) {
        const int idx = base + i;
        if (idx < n) cur[idx] = run;   // cursor = segment START (unpadded)
        run += v[i];
    }
}

// ---- Phase C: CSR fill, per-(range,chunk,rel) block, LDS cursor ----
__global__ __launch_bounds__(512) void fill_ranges(
        const int* __restrict__ s0p, const int* __restrict__ d0p, int e0,
        const int* __restrict__ s1p, const int* __restrict__ d1p, int e1,
        const int* __restrict__ s2p, const int* __restrict__ d2p, int e2,
        const int* __restrict__ cursor, const int* __restrict__ hist,
        int NP, int RB,
        int* __restrict__ csrbase, int off1, int off2) {
    __shared__ int cur[MAXRB];
    const int rel = blockIdx.z;
    const int* src = rel == 0 ? s0p : (rel == 1 ? s1p : s2p);
    const int* dst = rel == 0 ? d0p : (rel == 1 ? d1p : d2p);
    const int E = rel == 0 ? e0 : (rel == 1 ? e1 : e2);
    int* csr = csrbase + (rel == 0 ? 0 : (rel == 1 ? off1 : off2));
    const int c = blockIdx.y;
    const int lo = blockIdx.x * RB;
    const u32 rbu = (u32)RB;
    const int tid = threadIdx.x;
    const int* gc = cursor + (size_t)rel * NP + lo;
    const int* go = hist + ((size_t)(2 * rel + 1) * NCHUNK + c) * NP + lo;
    for (int i = tid; i < RB; i += 512) cur[i] = gc[i] + go[i];
    __syncthreads();
    const int ec = (((E + NCHUNK - 1) / NCHUNK) + 3) & ~3;
    const int s0 = c * ec;
    const int s1 = (s0 + ec) < E ? (s0 + ec) : E;
    if (s1 > s0) {
        const int n4 = (s1 - s0) >> 2;
        const int4* d4 = reinterpret_cast<const int4*>(dst + s0);
        const int4* s4 = reinterpret_cast<const int4*>(src + s0);
        for (int i = tid; i < n4; i += 512) {
            const int4 D = d4[i], S = s4[i];
            u32 ux = (u32)(D.x - lo); if (ux < rbu) { int p = atomicAdd(&cur[ux], 1); csr[p] = S.x; }
            u32 uy = (u32)(D.y - lo); if (uy < rbu) { int p = atomicAdd(&cur[uy], 1); csr[p] = S.y; }
            u32 uz = (u32)(D.z - lo); if (uz < rbu) { int p = atomicAdd(&cur[uz], 1); csr[p] = S.z; }
            u32 uw = (u32)(D.w - lo); if (uw < rbu) { int p = atomicAdd(&cur[uw], 1); csr[p] = S.w; }
        }
        for (int j = s0 + (n4 << 2) + tid; j < s1; j += 512) {
            const u32 u = (u32)(dst[j] - lo);
            if (u < rbu) { const int p = atomicAdd(&cur[u], 1); csr[p] = src[j]; }
        }
    }
}

// -------- all weight transposes in ONE kernel (bf16 [N][K] from [K][N]) ---
__global__ __launch_bounds__(256) void wt_all(
        u16* __restrict__ Wt1u, const float* __restrict__ W1_rates,
        const float* __restrict__ W1_fol,
        u16* __restrict__ Wt1i, const float* __restrict__ W1_rated,
        u16* __restrict__ Wt2u, const float* __restrict__ W2_rates,
        const float* __restrict__ W2_fol,
        u16* __restrict__ Wt2i, const float* __restrict__ W2_rated) {
    int i = blockIdx.x * 256 + threadIdx.x;
    if (i < 65536) {                      // Wt1u [256][256]
        const int n = i >> 8, k = i & 255;
        const float v = (n < 128) ? W1_rates[k * 128 + n] : W1_fol[k * 128 + (n - 128)];
        Wt1u[(size_t)n * 256 + k] = f2bf(v);
        return;
    }
    i -= 65536;
    if (i < 16384) {                      // Wt1i [128][128]
        const int n = i >> 7, k = i & 127;
        Wt1i[(size_t)n * 128 + k] = f2bf(W1_rated[k * 128 + n]);
        return;
    }
    i -= 16384;
    if (i < 16384) {                      // Wt2u [128][128]
        const int n = i >> 7, k = i & 127;
        const float v = (n < 64) ? W2_rates[k * 64 + n] : W2_fol[k * 64 + (n - 64)];
        Wt2u[(size_t)n * 128 + k] = f2bf(v);
        return;
    }
    i -= 16384;
    if (i < 8192) {                       // Wt2i [64][128]
        const int n = i >> 7, k = i & 127;
        Wt2i[(size_t)n * 128 + k] = f2bf(W2_rated[k * 64 + n]);
    }
}

// -------- generic MFMA GEMM body: T = bf16((X @ Wt^T) * inv[:,None]) ------
// 256 threads; wave grid WM x WN (BM=WM*64, BN=WN*64); full N per block
// (no column split -> A staged once). lbuf carved into lA[BM][64] +
// lB[BN][64], XOR-swizzled. K runtime (multiple of 64).
template<int WM, int WN, bool A_BF16>
__device__ __forceinline__ void gemm_body(
        u16* __restrict__ lbuf,
        const void* __restrict__ Xv, const u16* __restrict__ Wt,
        const float* __restrict__ invA, const float* __restrict__ invB,
        int nsplit, u16* __restrict__ T, int M, int TN, int K, int bx) {
    constexpr int BM = WM * 64, BN = WN * 64;
    constexpr int BLK = WM * WN * 64;   // must equal blockDim.x (256)
    constexpr int CA = 8 / WN;          // A chunks per thread
    constexpr int CB = 8 / WM;          // B chunks per thread
    u16* lA = lbuf;
    u16* lB = lbuf + BM * 64;
    const int tid = threadIdx.x;
    const int row0 = bx * BM;
    const int wid = tid >> 6, lane = tid & 63;
    const int wm = wid / WN, wn = wid % WN;
    const int l15 = lane & 15, lhi = lane >> 4;

    f32x4 acc[4][4] = {};

    for (int kk = 0; kk < K; kk += 64) {
        __syncthreads();
#pragma unroll
        for (int c = 0; c < CA; ++c) {
            const int cid = tid + c * BLK;
            const int row = cid >> 3, kc = cid & 7;
            const int grow = row0 + row;
            uint4 u = make_uint4(0, 0, 0, 0);
            if (A_BF16) {
                if (grow < M)
                    u = *reinterpret_cast<const uint4*>(
                        (const u16*)Xv + (size_t)grow * K + kk + kc * 8);
            } else {
                if (grow < M) {
                    const float* xp = (const float*)Xv + (size_t)grow * K + kk + kc * 8;
                    const float4 v0 = *reinterpret_cast<const float4*>(xp);
                    const float4 v1 = *reinterpret_cast<const float4*>(xp + 4);
                    u.x = pack2(v0.x, v0.y); u.y = pack2(v0.z, v0.w);
                    u.z = pack2(v1.x, v1.y); u.w = pack2(v1.z, v1.w);
                }
            }
            *reinterpret_cast<uint4*>(&lA[row * 64 + ((kc ^ (row & 7)) << 3)]) = u;
        }
#pragma unroll
        for (int c = 0; c < CB; ++c) {
            const int cid = tid + c * BLK;
            const int n = cid >> 3, kc = cid & 7;
            const uint4 u = *reinterpret_cast<const uint4*>(
                Wt + (size_t)n * K + kk + kc * 8);
            *reinterpret_cast<uint4*>(&lB[n * 64 + ((kc ^ (n & 7)) << 3)]) = u;
        }
        __syncthreads();
#pragma unroll
        for (int ks = 0; ks < 2; ++ks) {
            const int cb = ks * 4 + lhi;
            bf16x8 af[4], bfr[4];
#pragma unroll
            for (int fm = 0; fm < 4; ++fm) {
                const int r = wm * 64 + fm * 16 + l15;
                const uint4 u = *reinterpret_cast<const uint4*>(
                    &lA[r * 64 + ((cb ^ (r & 7)) << 3)]);
                af[fm] = __builtin_bit_cast(bf16x8, u);
            }
#pragma unroll
            for (int fn = 0; fn < 4; ++fn) {
                const int r = wn * 64 + fn * 16 + l15;
                const uint4 u = *reinterpret_cast<const uint4*>(
                    &lB[r * 64 + ((cb ^ (r & 7)) << 3)]);
                bfr[fn] = __builtin_bit_cast(bf16x8, u);
            }
#pragma unroll
            for (int fm = 0; fm < 4; ++fm)
#pragma unroll
                for (int fn = 0; fn < 4; ++fn)
                    acc[fm][fn] = __builtin_amdgcn_mfma_f32_16x16x32_bf16(
                        af[fm], bfr[fn], acc[fm][fn], 0, 0, 0);
        }
    }

    const int colw = wn * 64;
    const float* invp = (colw >= nsplit) ? invB : invA;
#pragma unroll
    for (int fm = 0; fm < 4; ++fm) {
#pragma unroll
        for (int r4 = 0; r4 < 4; ++r4) {
            const int grow = row0 + wm * 64 + fm * 16 + lhi * 4 + r4;
            if (grow < M) {
                const float s = invp[grow];
#pragma unroll
                for (int fn = 0; fn < 4; ++fn) {
                    const int col = colw + fn * 16 + l15;
                    T[(size_t)grow * TN + col] = f2bf(acc[fm][fn][r4] * s);
                }
            }
        }
    }
}

// ---- merged L1 GEMMs: y=0 user (BM64xBN256, K=256), y=1 item (128x128) ---
__global__ __launch_bounds__(256) void gemm_l1(
        const float* __restrict__ Xu, const u16* __restrict__ Wt1u,
        const float* __restrict__ Xi, const u16* __restrict__ Wt1i,
        const float* __restrict__ inv0, const float* __restrict__ inv4,
        const float* __restrict__ inv2,
        u16* __restrict__ t1u, u16* __restrict__ t1i,
        int nU, int nI, int gbI) {
    __shared__ u16 lbuf[20480];   // 40 KB
    if (blockIdx.y == 0) {
        gemm_body<1, 4, false>(lbuf, Xu, Wt1u, inv0, inv4, 128, t1u, nU, 256, 256, blockIdx.x);
    } else {
        if ((int)blockIdx.x >= gbI) return;
        gemm_body<2, 2, false>(lbuf, Xi, Wt1i, inv2, inv2, 1 << 30, t1i, nI, 128, 128, blockIdx.x);
    }
}

// ---- merged L2 GEMMs: y=0 user (128x128), y=1 item (256x64), K=128 ------
__global__ __launch_bounds__(256) void gemm_l2(
        const u16* __restrict__ aggU, const u16* __restrict__ Wt2u,
        const u16* __restrict__ aggI, const u16* __restrict__ Wt2i,
        const float* __restrict__ inv0, const float* __restrict__ inv4,
        const float* __restrict__ inv2,
        u16* __restrict__ t2u, u16* __restrict__ t2i,
        int nU, int nI, int gbI) {
    __shared__ u16 lbuf[20480];   // 40 KB
    if (blockIdx.y == 0) {
        gemm_body<2, 2, true>(lbuf, aggU, Wt2u, inv0, inv4, 64, t2u, nU, 128, 128, blockIdx.x);
    } else {
        if ((int)blockIdx.x >= gbI) return;
        gemm_body<4, 1, true>(lbuf, aggI, Wt2i, inv2, inv2, 1 << 30, t2i, nI, 64, 128, blockIdx.x);
    }
}

// -------- pull-aggregation over bf16 T, one wave per dst node -----------
template<int F>
__device__ __forceinline__ void gather_rel(
        const u16* __restrict__ T, int strideT, int offT,
        const int* __restrict__ csr, int beg, int cnt, int Z, int lane,
        float& s0, float& s1) {
    const int* cp = csr + beg;
    const int loff = (F == 128) ? lane * 2 : lane;
    for (int e = 0; e < cnt; e += 8) {
        int idx[8];
#pragma unroll
        for (int i = 0; i < 8; ++i) {
            const int t = cp[e + i];
            idx[i] = __builtin_amdgcn_readfirstlane((e + i < cnt) ? t : Z);
        }
        if (F == 128) {
            u32 v[8];
#pragma unroll
            for (int i = 0; i < 8; ++i)
                v[i] = *reinterpret_cast<const u32*>(
                    T + (size_t)idx[i] * strideT + offT + loff);
#pragma unroll
            for (int i = 0; i < 8; ++i) {
                union { u32 u; float f; } lo, hi;
                lo.u = v[i] << 16;
                hi.u = v[i] & 0xffff0000u;
                s0 += lo.f; s1 += hi.f;
            }
        } else {
            u16 v[8];
#pragma unroll
            for (int i = 0; i < 8; ++i)
                v[i] = T[(size_t)idx[i] * strideT + offT + loff];
#pragma unroll
            for (int i = 0; i < 8; ++i) {
                union { u32 u; float f; } c;
                c.u = ((u32)v[i]) << 16;
                s0 += c.f;
            }
        }
    }
}

template<int F, bool TWO, bool RELU, bool BF16OUT>
__device__ __forceinline__ void gather_node(
        const u16* __restrict__ Ta, int strideA, int offA,
        const int* __restrict__ csrA, const int* __restrict__ curA,
        const int* __restrict__ degA, const float* __restrict__ invA,
        const float* __restrict__ biasA,
        const u16* __restrict__ Tb, int strideB, int offB,
        const int* __restrict__ csrB, const int* __restrict__ curB,
        const int* __restrict__ degB, const float* __restrict__ invB,
        const float* __restrict__ biasB,
        void* __restrict__ outv, int Z, int wid, int lane) {
    float r0, r1 = 0.f;
    {
        const int cnt = degA[wid];
        const int beg = curA[wid];
        float s0 = 0.f, s1 = 0.f;
        gather_rel<F>(Ta, strideA, offA, csrA, beg, cnt, Z, lane, s0, s1);
        const float a = invA[wid];
        if (F == 128) {
            const float2 b = *reinterpret_cast<const float2*>(biasA + lane * 2);
            r0 = s0 * a + b.x; r1 = s1 * a + b.y;
        } else {
            r0 = s0 * a + biasA[lane];
        }
    }
    if (TWO) {
        const int cnt = degB[wid];
        const int beg = curB[wid];
        float s0 = 0.f, s1 = 0.f;
        gather_rel<F>(Tb, strideB, offB, csrB, beg, cnt, Z, lane, s0, s1);
        const float a = invB[wid];
        if (F == 128) {
            const float2 b = *reinterpret_cast<const float2*>(biasB + lane * 2);
            r0 += s0 * a + b.x; r1 += s1 * a + b.y;
        } else {
            r0 += s0 * a + biasB[lane];
        }
    }
    if (RELU) { r0 = fmaxf(r0, 0.f); r1 = fmaxf(r1, 0.f); }
    if (BF16OUT) {
        if (F == 128)
            ((u32*)outv)[(size_t)wid * 64 + lane] = pack2(r0, r1);
        else
            ((u16*)outv)[(size_t)wid * 64 + lane] = f2bf(r0);
    } else {
        if (F == 128) {
            float2 o; o.x = r0; o.y = r1;
            *reinterpret_cast<float2*>((float*)outv + (size_t)wid * 128 + lane * 2) = o;
        } else {
            ((float*)outv)[(size_t)wid * 64 + lane] = r0;
        }
    }
}

// ---- merged L1 gathers: y=0 item(rates), y=1 user(rated+fol) ----
__global__ __launch_bounds__(256) void gather_l1(
        const u16* __restrict__ t1u, const u16* __restrict__ t1i,
        const int* __restrict__ csr0, const int* __restrict__ cur0,
        const int* __restrict__ deg1, const float* __restrict__ inv1,
        const float* __restrict__ b1_rates,
        const int* __restrict__ csr1, const int* __restrict__ cur1,
        const int* __restrict__ deg3, const float* __restrict__ inv3,
        const float* __restrict__ b1_rated,
        const int* __restrict__ csr2, const int* __restrict__ cur2,
        const int* __restrict__ deg5, const float* __restrict__ inv5,
        const float* __restrict__ b1_fol,
        u16* __restrict__ aggI, u16* __restrict__ aggU,
        int Z, int nI, int nU) {
    const int wid = (blockIdx.x * 256 + threadIdx.x) >> 6;
    const int lane = threadIdx.x & 63;
    if (blockIdx.y == 0) {
        if (wid >= nI) return;
        gather_node<128, false, true, true>(
            t1u, 256, 0, csr0, cur0, deg1, inv1, b1_rates,
            nullptr, 0, 0, nullptr, nullptr, nullptr, nullptr, nullptr,
            aggI, Z, wid, lane);
    } else {
        if (wid >= nU) return;
        gather_node<128, true, true, true>(
            t1i, 128, 0, csr1, cur1, deg3, inv3, b1_rated,
            t1u, 256, 128, csr2, cur2, deg5, inv5, b1_fol,
            aggU, Z, wid, lane);
    }
}

// ---- merged L2 gathers: y=0 item -> o_item, y=1 user -> o_user ----
__global__ __launch_bounds__(256) void gather_l2(
        const u16* __restrict__ t2u, const u16* __restrict__ t2i,
        const int* __restrict__ csr0, const int* __restrict__ cur0,
        const int* __restrict__ deg1, const float* __restrict__ inv1,
        const float* __restrict__ b2_rates,
        const int* __restrict__ csr1, const int* __restrict__ cur1,
        const int* __restrict__ deg3, const float* __restrict__ inv3,
        const float* __restrict__ b2_rated,
        const int* __restrict__ csr2, const int* __restrict__ cur2,
        const int* __restrict__ deg5, const float* __restrict__ inv5,
        const float* __restrict__ b2_fol,
        float* __restrict__ o_item, float* __restrict__ o_user,
        int Z, int nI, int nU) {
    const int wid = (blockIdx.x * 256 + threadIdx.x) >> 6;
    const int lane = threadIdx.x & 63;
    if (blockIdx.y == 0) {
        if (wid >= nI) return;
        gather_node<64, false, false, false>(
            t2u, 128, 0, csr0, cur0, deg1, inv1, b2_rates,
            nullptr, 0, 0, nullptr, nullptr, nullptr, nullptr, nullptr,
            o_item, Z, wid, lane);
    } else {
        if (wid >= nU) return;
        gather_node<64, true, false, false>(
            t2i, 64, 0, csr1, cur1, deg3, inv3, b2_rated,
            t2u, 128, 64, csr2, cur2, deg5, inv5, b2_fol,
            o_user, Z, wid, lane);
    }
}

extern "C" void kernel_launch(void* const* d_in, const int* in_sizes, int n_in,
                              void* d_out, int out_size, void* d_ws, size_t ws_size,
                              hipStream_t stream) {
    const float* feat_user = (const float*)d_in[0];
    const float* feat_item = (const float*)d_in[1];
    const int* rates_src = (const int*)d_in[2];
    const int* rates_dst = (const int*)d_in[3];
    const int* rated_src = (const int*)d_in[4];
    const int* rated_dst = (const int*)d_in[5];
    const int* fol_src   = (const int*)d_in[6];
    const int* fol_dst   = (const int*)d_in[7];
    const float* W1_rates = (const float*)d_in[8];
    const float* b1_rates = (const float*)d_in[9];
    const float* W1_rated = (const float*)d_in[10];
    const float* b1_rated = (const float*)d_in[11];
    const float* W1_fol   = (const float*)d_in[12];
    const float* b1_fol   = (const float*)d_in[13];
    const float* W2_rates = (const float*)d_in[14];
    const float* b2_rates = (const float*)d_in[15];
    const float* W2_rated = (const float*)d_in[16];
    const float* b2_rated = (const float*)d_in[17];
    const float* W2_fol   = (const float*)d_in[18];
    const float* b2_fol   = (const float*)d_in[19];

    const int n_user = in_sizes[0] / IN_USER;
    const int n_item = in_sizes[1] / IN_ITEM;
    const int E0 = in_sizes[2];
    const int E1 = in_sizes[4];
    const int E2 = in_sizes[6];
    const int nmax = n_user > n_item ? n_user : n_item;
    const int Z = nmax;   // zero-row index (tail-mask target)

    // ---- workspace layout ----
    const size_t NP = ((size_t)(nmax + 1023) / 1024) * 1024;   // 100352
    int*   deg     = (int*)d_ws;                   // [6][NP]
    float* inv     = (float*)(deg + 6 * NP);       // [6][NP]
    int*   cursor  = (int*)(inv + 6 * NP);         // [3][NP]  (segment starts)
    int*   partial = cursor + 3 * NP;              // [3][128]
    int*   csr  = partial + 3 * 128;               // [E0+E1+E2] (unpadded)
    int*   csr0 = csr;
    int*   csr1 = csr + E0;
    int*   csr2 = csr + E0 + E1;
    u16* Wt1u = (u16*)(csr + E0 + E1 + E2);        // [256][256]
    u16* Wt1i = Wt1u + 256 * 256;                  // [128][128]
    u16* Wt2u = Wt1i + 128 * 128;                  // [128][128]
    u16* Wt2i = Wt2u + 128 * 128;                  // [64][128]
    u16* t1u  = Wt2i + 64 * 128;                   // [nmax+1][256] bf16
    u16* t1i  = t1u + (size_t)(nmax + 1) * 256;    // [nmax+1][128] bf16
    u16* aggU = t1i + (size_t)(nmax + 1) * 128;    // [n_user][128] bf16
    u16* aggI = aggU + (size_t)nmax * 128;         // [n_item][128] bf16
    u16* t2u  = t1i;   // alias: t1i dead after user_L1 gather
    u16* t2i  = t1u;   // alias: t1u dead after user_L1 gather
    // hist[6][NCHUNK][NP] aliases t1u's first 38.5MB (dead before gemm_l1;
    // t1u's Z row at byte 51.2MB is beyond the hist region)
    int* hist = (int*)t1u;

    float* o_user = (float*)d_out;
    float* o_item = o_user + (size_t)n_user * OUTF;

    hipMemsetAsync(t1u + (size_t)Z * 256, 0, 512, stream);   // beyond hist area
    hipMemsetAsync(t1i + (size_t)Z * 128, 0, 256, stream);   // == t2u Z row

    // array idx: 0=rates_src(user) 1=rates_dst(item) 2=rated_src(item)
    //            3=rated_dst(user) 4=fol_src(user)   5=fol_dst(user)
    const int RB = (int)(NP / NRANGE);   // 12544 == MAXRB
    hist_ranges<<<dim3(NRANGE, NCHUNK, 6), 512, 0, stream>>>(
        rates_src, E0, rates_dst, E0, rated_src, E1,
        rated_dst, E1, fol_src, E2, fol_dst, E2, hist, (int)NP, RB);
    hist_reduce<<<dim3((int)(NP + 255) / 256, 6), 256, 0, stream>>>(
        hist, deg, inv, (int)NP);

    wt_all<<<(65536 + 16384 + 16384 + 8192 + 255) / 256, 256, 0, stream>>>(
        Wt1u, W1_rates, W1_fol, Wt1i, W1_rated,
        Wt2u, W2_rates, W2_fol, Wt2i, W2_rated);

    // ---- CSR build (by destination, unpadded segments) ----
    const int nblk = (int)(NP / 1024);
    scan_part<<<dim3(nblk, 3), 256, 0, stream>>>(
        deg + 1 * NP, deg + 3 * NP, deg + 5 * NP, n_item, n_user, n_user, partial, nblk);
    scan_mid<<<3, 128, 0, stream>>>(partial, nblk);
    scan_final<<<dim3(nblk, 3), 256, 0, stream>>>(
        deg + 1 * NP, deg + 3 * NP, deg + 5 * NP, n_item, n_user, n_user, partial,
        cursor + 0 * NP, cursor + 1 * NP, cursor + 2 * NP, nblk);
    fill_ranges<<<dim3(NRANGE, NCHUNK, 3), 512, 0, stream>>>(
        rates_src, rates_dst, E0, rated_src, rated_dst, E1,
        fol_src, fol_dst, E2, cursor, hist, (int)NP, RB, csr, E0, E0 + E1);

    // grids
    const int gbU1 = (n_user + 63) / 64;      // 1563 (BM=64)
    const int gbI1 = (n_item + 127) / 128;    // 782  (BM=128)
    const int gbU2 = (n_user + 127) / 128;    // 782  (BM=128)
    const int gbI2 = (n_item + 255) / 256;    // 391  (BM=256)
    const int gw   = (nmax * 64 + 255) / 256; // gather blocks per plane

    // ---- layer 1: merged GEMMs, then merged gathers ----
    gemm_l1<<<dim3(gbU1, 2), 256, 0, stream>>>(
        feat_user, Wt1u, feat_item, Wt1i,
        inv + 0 * NP, inv + 4 * NP, inv + 2 * NP,
        t1u, t1i, n_user, n_item, gbI1);

    gather_l1<<<dim3(gw, 2), 256, 0, stream>>>(
        t1u, t1i,
        csr0, cursor + 0 * NP, deg + 1 * NP, inv + 1 * NP, b1_rates,
        csr1, cursor + 1 * NP, deg + 3 * NP, inv + 3 * NP, b1_rated,
        csr2, cursor + 2 * NP, deg + 5 * NP, inv + 5 * NP, b1_fol,
        aggI, aggU, Z, n_item, n_user);

    // t2i (= t1u region, stride 64) Z row: slot held live t1u data until now
    hipMemsetAsync(t2i + (size_t)Z * 64, 0, 128, stream);

    // ---- layer 2: merged GEMMs, then merged gathers (into d_out) ----
    gemm_l2<<<dim3(gbU2, 2), 256, 0, stream>>>(
        aggU, Wt2u, aggI, Wt2i,
        inv + 0 * NP, inv + 4 * NP, inv + 2 * NP,
        t2u, t2i, n_user, n_item, gbI2);

    gather_l2<<<dim3(gw, 2), 256, 0, stream>>>(
        t2u, t2i,
        csr0, cursor + 0 * NP, deg + 1 * NP, inv + 1 * NP, b2_rates,
        csr1, cursor + 1 * NP, deg + 3 * NP, inv + 3 * NP, b2_rated,
        csr2, cursor + 2 * NP, deg + 5 * NP, inv + 5 * NP, b2_fol,
        o_item, o_user, Z, n_item, n_user);
}